// Round 14
// baseline (424.153 us; speedup 1.0000x reference)
//
#include <hip/hip_runtime.h>
#include <math.h>

#define NG 256
#define NBK 512          // sort buckets
#define BCAP 3584        // per-bucket staging capacity (mean 3125, +8 sigma)

static __device__ __forceinline__ int bucket_lo(int p, int n) {
    return (int)(((long long)p * n + NBK - 1) / NBK);   // ceil(p*n/NBK)
}

// ---- bf16 helpers (tables stored as packed pairs in uint) ----
static __device__ __forceinline__ float blo(unsigned u) {
    return __uint_as_float(u << 16);
}
static __device__ __forceinline__ float bhi(unsigned u) {
    return __uint_as_float(u & 0xFFFF0000u);
}
static __device__ __forceinline__ unsigned packbf(float a, float b) {
    unsigned ua = __float_as_uint(a);
    ua = (ua + 0x7FFFu + ((ua >> 16) & 1u)) >> 16;          // RNE, low half
    unsigned ub = __float_as_uint(b);
    ub = (ub + 0x7FFFu + ((ub >> 16) & 1u)) & 0xFFFF0000u;  // RNE, high half
    return ua | ub;
}

// ---------------- bucket cursor init ----------------
__global__ void zero_bcur(int* bcur) {
    int i = blockIdx.x * blockDim.x + threadIdx.x;
    if (i < NBK) bcur[i] = i * BCAP;
}

// ------- phase A: bucket edges by dst; staged record = (src<<8)|local_dst --
__global__ void bucketA(const int* __restrict__ src, const int* __restrict__ dst,
                        int* bcur, unsigned* stage, int e, int n) {
    __shared__ int cnt[NBK];
    __shared__ int base[NBK];
    int nb = gridDim.x;
    int c0 = (int)((long long)blockIdx.x * e / nb);
    int c1 = (int)((long long)(blockIdx.x + 1) * e / nb);
    for (int k = threadIdx.x; k < NBK; k += blockDim.x) cnt[k] = 0;
    __syncthreads();
    for (int i = c0 + threadIdx.x; i < c1; i += blockDim.x) {
        int d = dst[i];
        int p = (int)((long long)d * NBK / n);
        atomicAdd(&cnt[p], 1);
    }
    __syncthreads();
    for (int k = threadIdx.x; k < NBK; k += blockDim.x)
        base[k] = atomicAdd(&bcur[k], cnt[k]);
    __syncthreads();
    for (int k = threadIdx.x; k < NBK; k += blockDim.x) cnt[k] = 0;
    __syncthreads();
    for (int i = c0 + threadIdx.x; i < c1; i += blockDim.x) {
        int s = src[i], d = dst[i];
        int p = (int)((long long)d * NBK / n);
        int ldst = d - bucket_lo(p, n);           // < 196, fits 8 bits
        int lp = atomicAdd(&cnt[p], 1);
        stage[base[p] + lp] = ((unsigned)s << 8) | (unsigned)ldst;
    }
}

// ======= fused CSR finish: hist + scan + rowptr + dinv + scatter ========
__global__ void fillB2(const unsigned* __restrict__ stage,
                       const int* __restrict__ bcur,
                       int* __restrict__ rowptr, float* __restrict__ dinv,
                       int* __restrict__ csrs, int n, int e) {
    __shared__ int ldeg[256];
    __shared__ int loff[256];
    __shared__ int bstart;
    int p = blockIdx.x;
    int t = threadIdx.x;
    int lo = bucket_lo(p, n), hi = bucket_lo(p + 1, n);
    int nloc = hi - lo;                           // <= 196

    // ---- bucketStart[p] = sum of counts of buckets < p ----
    {
        int acc = 0;
        for (int k = t; k < p; k += 256) acc += bcur[k] - k * BCAP;
        ldeg[t] = acc;
        __syncthreads();
        for (int off = 128; off > 0; off >>= 1) {
            if (t < off) ldeg[t] += ldeg[t + off];
            __syncthreads();
        }
        if (t == 0) bstart = ldeg[0];
        __syncthreads();
    }

    // ---- local degree histogram ----
    if (t < 256) ldeg[t] = 0;
    __syncthreads();
    int s0 = p * BCAP, s1 = bcur[p];
    for (int i = s0 + t; i < s1; i += 256)
        atomicAdd(&ldeg[stage[i] & 255u], 1);
    __syncthreads();

    // ---- exclusive scan (256-wide) -> rowptr, dinv, cursors ----
    int v = (t < nloc) ? ldeg[t] : 0;
    loff[t] = v;
    __syncthreads();
    for (int off = 1; off < 256; off <<= 1) {
        int u = (t >= off) ? loff[t - off] : 0;
        __syncthreads();
        loff[t] += u;
        __syncthreads();
    }
    if (t < nloc) {
        int start = bstart + loff[t] - v;         // exclusive
        rowptr[lo + t] = start;
        dinv[lo + t] = rsqrtf((float)v + 1.0f);   // +1 self-loop
    }
    if (p == NBK - 1 && t == 0) rowptr[n] = e;
    __syncthreads();
    if (t < nloc) ldeg[t] = bstart + loff[t] - v; // reuse as cursors
    __syncthreads();

    // ---- scatter ----
    for (int i = s0 + t; i < s1; i += 256) {
        unsigned pk = stage[i];
        int ldst = (int)(pk & 255u);
        int pos = atomicAdd(&ldeg[ldst], 1);
        csrs[pos] = (int)(pk >> 8);
    }
}

// ---------------- layer-1 aggregate on raw x (5-dim), thread = node ------
__global__ void gather5(const int* __restrict__ rowptr,
                        const int* __restrict__ csrs,
                        const float* __restrict__ dinv,
                        const float* __restrict__ x,
                        float* __restrict__ z, int n) {
    int i = blockIdx.x * blockDim.x + threadIdx.x;
    if (i >= n) return;
    float di = dinv[i];
    float ws = di * di;
    const float* xr = x + (size_t)i * 5;
    float4 x4 = *(const float4*)(xr);
    float a0 = x4.x * ws, a1 = x4.y * ws, a2 = x4.z * ws,
          a3 = x4.w * ws, a4 = xr[4] * ws;
    int end = rowptr[i + 1];
    for (int j = rowptr[i]; j < end; ++j) {
        int s = csrs[j];
        float w = dinv[s] * di;
        const float* r = x + (size_t)s * 5;
        float4 r4 = *(const float4*)(r);
        float r1 = r[4];
        a0 = fmaf(w, r4.x, a0);
        a1 = fmaf(w, r4.y, a1);
        a2 = fmaf(w, r4.z, a2);
        a3 = fmaf(w, r4.w, a3);
        a4 = fmaf(w, r1, a4);
    }
    float* zr = z + (size_t)i * 5;
    zr[0] = a0; zr[1] = a1; zr[2] = a2; zr[3] = a3; zr[4] = a4;
}

// ---- transform epilogue: bias/relu/scale + fp32 or packed-bf16 store ----
template<int DOUT, bool BR, bool SCALE, bool OUTBF>
static __device__ __forceinline__ void emit(float o[8], const float* b, int c,
                                            float dsc, void* out, int i) {
    if (BR) {
        float4 b0 = *(const float4*)(b + c * 8);
        float4 b1 = *(const float4*)(b + c * 8 + 4);
        o[0] = fmaxf(o[0] + b0.x, 0.f); o[1] = fmaxf(o[1] + b0.y, 0.f);
        o[2] = fmaxf(o[2] + b0.z, 0.f); o[3] = fmaxf(o[3] + b0.w, 0.f);
        o[4] = fmaxf(o[4] + b1.x, 0.f); o[5] = fmaxf(o[5] + b1.y, 0.f);
        o[6] = fmaxf(o[6] + b1.z, 0.f); o[7] = fmaxf(o[7] + b1.w, 0.f);
    }
    if (SCALE) {
#pragma unroll
        for (int q = 0; q < 8; ++q) o[q] *= dsc;
    }
    if (OUTBF) {
        uint4 pk;
        pk.x = packbf(o[0], o[1]); pk.y = packbf(o[2], o[3]);
        pk.z = packbf(o[4], o[5]); pk.w = packbf(o[6], o[7]);
        *(uint4*)((unsigned*)out + (size_t)i * (DOUT / 2) + c * 4) = pk;
    } else {
        float* op = (float*)out + (size_t)i * DOUT + c * 8;
        float4 o0 = {o[0], o[1], o[2], o[3]};
        float4 o1 = {o[4], o[5], o[6], o[7]};
        *(float4*)(op) = o0;
        *(float4*)(op + 4) = o1;
    }
}

// ------- dense transform, 8 outputs x NODES nodes per thread -------------
// global W float4 loads (L1/L2-hot); row loads software-pipelined
template<int K, int DOUT, bool BR, bool SCALE, bool OUTBF, int NODES>
__global__ void transformB(const float* __restrict__ xin,
                           const float* __restrict__ W,
                           const float* __restrict__ b,
                           const float* __restrict__ dinv,
                           void* __restrict__ out, int n) {
    const int C = DOUT / 8;
    int tid = blockIdx.x * blockDim.x + threadIdx.x;
    int grp = tid / C;
    int c = tid % C;
    int i0 = grp * NODES;
    if (i0 >= n) return;
    float acc[NODES][8];
#pragma unroll
    for (int nn = 0; nn < NODES; ++nn)
#pragma unroll
        for (int q = 0; q < 8; ++q) acc[nn][q] = 0.0f;

    static_assert(K % 4 == 0, "K multiple of 4");
    int idx[NODES];
#pragma unroll
    for (int nn = 0; nn < NODES; ++nn)
        idx[nn] = (i0 + nn < n) ? i0 + nn : n - 1;

    float4 r[NODES];
#pragma unroll
    for (int nn = 0; nn < NODES; ++nn)
        r[nn] = *(const float4*)(xin + (size_t)idx[nn] * K);

    for (int k0 = 0; k0 < K; k0 += 4) {
        float4 rn[NODES];
        if (k0 + 4 < K) {
#pragma unroll
            for (int nn = 0; nn < NODES; ++nn)
                rn[nn] = *(const float4*)(xin + (size_t)idx[nn] * K + k0 + 4);
        }
#pragma unroll
        for (int kk = 0; kk < 4; ++kk) {
            const float* wp = W + (size_t)(k0 + kk) * DOUT + c * 8;
            float4 w0 = *(const float4*)(wp);
            float4 w1 = *(const float4*)(wp + 4);
#pragma unroll
            for (int nn = 0; nn < NODES; ++nn) {
                float v = (&r[nn].x)[kk];
                acc[nn][0] = fmaf(v, w0.x, acc[nn][0]);
                acc[nn][1] = fmaf(v, w0.y, acc[nn][1]);
                acc[nn][2] = fmaf(v, w0.z, acc[nn][2]);
                acc[nn][3] = fmaf(v, w0.w, acc[nn][3]);
                acc[nn][4] = fmaf(v, w1.x, acc[nn][4]);
                acc[nn][5] = fmaf(v, w1.y, acc[nn][5]);
                acc[nn][6] = fmaf(v, w1.z, acc[nn][6]);
                acc[nn][7] = fmaf(v, w1.w, acc[nn][7]);
            }
        }
#pragma unroll
        for (int nn = 0; nn < NODES; ++nn) r[nn] = rn[nn];
    }
#pragma unroll
    for (int nn = 0; nn < NODES; ++nn) {
        if (i0 + nn >= n) break;
        float dsc = SCALE ? dinv[i0 + nn] : 1.0f;
        emit<DOUT, BR, SCALE, OUTBF>(acc[nn], b, c, dsc, out, i0 + nn);
    }
}

// ---- K=5 fp32-input transform (layer 1) --------------------------------
template<int DOUT, bool BR, bool SCALE, bool OUTBF, int NODES>
__global__ void transformB5(const float* __restrict__ xin,
                            const float* __restrict__ W,
                            const float* __restrict__ b,
                            const float* __restrict__ dinv,
                            void* __restrict__ out, int n) {
    const int C = DOUT / 8;
    int tid = blockIdx.x * blockDim.x + threadIdx.x;
    int grp = tid / C;
    int c = tid % C;
    int i0 = grp * NODES;
    if (i0 >= n) return;
    float r[NODES][5];
#pragma unroll
    for (int nn = 0; nn < NODES; ++nn) {
        int idx = i0 + nn < n ? i0 + nn : n - 1;
        const float* row = xin + (size_t)idx * 5;
#pragma unroll
        for (int k = 0; k < 5; ++k) r[nn][k] = row[k];
    }
    float acc[NODES][8];
#pragma unroll
    for (int nn = 0; nn < NODES; ++nn)
#pragma unroll
        for (int q = 0; q < 8; ++q) acc[nn][q] = 0.0f;
#pragma unroll
    for (int k = 0; k < 5; ++k) {
        const float* wp = W + (size_t)k * DOUT + c * 8;
        float4 w0 = *(const float4*)(wp);
        float4 w1 = *(const float4*)(wp + 4);
#pragma unroll
        for (int nn = 0; nn < NODES; ++nn) {
            float v = r[nn][k];
            acc[nn][0] = fmaf(v, w0.x, acc[nn][0]);
            acc[nn][1] = fmaf(v, w0.y, acc[nn][1]);
            acc[nn][2] = fmaf(v, w0.z, acc[nn][2]);
            acc[nn][3] = fmaf(v, w0.w, acc[nn][3]);
            acc[nn][4] = fmaf(v, w1.x, acc[nn][4]);
            acc[nn][5] = fmaf(v, w1.y, acc[nn][5]);
            acc[nn][6] = fmaf(v, w1.z, acc[nn][6]);
            acc[nn][7] = fmaf(v, w1.w, acc[nn][7]);
        }
    }
#pragma unroll
    for (int nn = 0; nn < NODES; ++nn) {
        if (i0 + nn >= n) break;
        float dsc = SCALE ? dinv[i0 + nn] : 1.0f;
        emit<DOUT, BR, SCALE, OUTBF>(acc[nn], b, c, dsc, out, i0 + nn);
    }
}

// ------- 64-dim gather from bf16 table (dinv pre-folded into table) ------
// z[i] = dinv[i] * (g[i] + sum_src g[s]);   8 lanes/node, 8 feats/lane
// 8-edge unroll (8 loads in flight), 4 accumulator sets
template<bool BR>
__global__ void gatherBF(const int* __restrict__ rowptr,
                         const int* __restrict__ csrs,
                         const float* __restrict__ dinv,
                         const float* __restrict__ b,
                         const unsigned* __restrict__ g,   // [n][32] packed bf16
                         float* __restrict__ z, int n) {
    int tid = blockIdx.x * blockDim.x + threadIdx.x;
    int i = tid >> 3;
    int c = tid & 7;
    if (i >= n) return;
    uint4 sv = *(const uint4*)(g + (size_t)i * 32 + c * 4);
    float a0[8], a1[8], a2[8], a3[8];
    a0[0] = blo(sv.x); a0[1] = bhi(sv.x); a0[2] = blo(sv.y); a0[3] = bhi(sv.y);
    a0[4] = blo(sv.z); a0[5] = bhi(sv.z); a0[6] = blo(sv.w); a0[7] = bhi(sv.w);
#pragma unroll
    for (int q = 0; q < 8; ++q) { a1[q] = 0.0f; a2[q] = 0.0f; a3[q] = 0.0f; }
    int j = rowptr[i], end = rowptr[i + 1];
    for (; j + 7 < end; j += 8) {
        uint4 v0 = *(const uint4*)(g + (size_t)csrs[j]     * 32 + c * 4);
        uint4 v1 = *(const uint4*)(g + (size_t)csrs[j + 1] * 32 + c * 4);
        uint4 v2 = *(const uint4*)(g + (size_t)csrs[j + 2] * 32 + c * 4);
        uint4 v3 = *(const uint4*)(g + (size_t)csrs[j + 3] * 32 + c * 4);
        uint4 v4 = *(const uint4*)(g + (size_t)csrs[j + 4] * 32 + c * 4);
        uint4 v5 = *(const uint4*)(g + (size_t)csrs[j + 5] * 32 + c * 4);
        uint4 v6 = *(const uint4*)(g + (size_t)csrs[j + 6] * 32 + c * 4);
        uint4 v7 = *(const uint4*)(g + (size_t)csrs[j + 7] * 32 + c * 4);
        a0[0] += blo(v0.x); a0[1] += bhi(v0.x); a0[2] += blo(v0.y); a0[3] += bhi(v0.y);
        a0[4] += blo(v0.z); a0[5] += bhi(v0.z); a0[6] += blo(v0.w); a0[7] += bhi(v0.w);
        a1[0] += blo(v1.x); a1[1] += bhi(v1.x); a1[2] += blo(v1.y); a1[3] += bhi(v1.y);
        a1[4] += blo(v1.z); a1[5] += bhi(v1.z); a1[6] += blo(v1.w); a1[7] += bhi(v1.w);
        a2[0] += blo(v2.x); a2[1] += bhi(v2.x); a2[2] += blo(v2.y); a2[3] += bhi(v2.y);
        a2[4] += blo(v2.z); a2[5] += bhi(v2.z); a2[6] += blo(v2.w); a2[7] += bhi(v2.w);
        a3[0] += blo(v3.x); a3[1] += bhi(v3.x); a3[2] += blo(v3.y); a3[3] += bhi(v3.y);
        a3[4] += blo(v3.z); a3[5] += bhi(v3.z); a3[6] += blo(v3.w); a3[7] += bhi(v3.w);
        a0[0] += blo(v4.x); a0[1] += bhi(v4.x); a0[2] += blo(v4.y); a0[3] += bhi(v4.y);
        a0[4] += blo(v4.z); a0[5] += bhi(v4.z); a0[6] += blo(v4.w); a0[7] += bhi(v4.w);
        a1[0] += blo(v5.x); a1[1] += bhi(v5.x); a1[2] += blo(v5.y); a1[3] += bhi(v5.y);
        a1[4] += blo(v5.z); a1[5] += bhi(v5.z); a1[6] += blo(v5.w); a1[7] += bhi(v5.w);
        a2[0] += blo(v6.x); a2[1] += bhi(v6.x); a2[2] += blo(v6.y); a2[3] += bhi(v6.y);
        a2[4] += blo(v6.z); a2[5] += bhi(v6.z); a2[6] += blo(v6.w); a2[7] += bhi(v6.w);
        a3[0] += blo(v7.x); a3[1] += bhi(v7.x); a3[2] += blo(v7.y); a3[3] += bhi(v7.y);
        a3[4] += blo(v7.z); a3[5] += bhi(v7.z); a3[6] += blo(v7.w); a3[7] += bhi(v7.w);
    }
    for (; j < end; ++j) {
        int s0 = csrs[j];
        uint4 v0 = *(const uint4*)(g + (size_t)s0 * 32 + c * 4);
        a0[0] += blo(v0.x); a0[1] += bhi(v0.x); a0[2] += blo(v0.y); a0[3] += bhi(v0.y);
        a0[4] += blo(v0.z); a0[5] += bhi(v0.z); a0[6] += blo(v0.w); a0[7] += bhi(v0.w);
    }
    float di = dinv[i];
    float o[8];
#pragma unroll
    for (int q = 0; q < 8; ++q) o[q] = di * ((a0[q] + a1[q]) + (a2[q] + a3[q]));
    if (BR) {
        float4 b0 = *(const float4*)(b + c * 8);
        float4 b1 = *(const float4*)(b + c * 8 + 4);
        o[0] = fmaxf(o[0] + b0.x, 0.f); o[1] = fmaxf(o[1] + b0.y, 0.f);
        o[2] = fmaxf(o[2] + b0.z, 0.f); o[3] = fmaxf(o[3] + b0.w, 0.f);
        o[4] = fmaxf(o[4] + b1.x, 0.f); o[5] = fmaxf(o[5] + b1.y, 0.f);
        o[6] = fmaxf(o[6] + b1.z, 0.f); o[7] = fmaxf(o[7] + b1.w, 0.f);
    }
    float* zp = z + (size_t)i * 64 + c * 8;
    float4 z0 = {o[0], o[1], o[2], o[3]};
    float4 z1 = {o[4], o[5], o[6], o[7]};
    *(float4*)(zp) = z0;
    *(float4*)(zp + 4) = z1;
}

// ------- pooling + FC + sigmoid: 4 waves per graph, LDS combine ---------
__global__ void pool(const float* __restrict__ h3, const int* __restrict__ batch,
                     const float* __restrict__ Wfc, const float* __restrict__ bfc,
                     float* __restrict__ out, int n) {
    int g = blockIdx.x;
    int lane = threadIdx.x & 63;
    int w = threadIdx.x >> 6;  // 0..3
    int lo = 0, hi = n;
    while (lo < hi) { int m = (lo + hi) >> 1; if (batch[m] < g) lo = m + 1; else hi = m; }
    int start = lo;
    hi = n;
    while (lo < hi) { int m = (lo + hi) >> 1; if (batch[m] < g + 1) lo = m + 1; else hi = m; }
    int end = lo;
    float a0 = 0.f, a1 = 0.f, a2 = 0.f, a3 = 0.f;
    int m = start + w;
    for (; m + 12 < end; m += 16) {
        a0 += h3[(size_t)m * 64 + lane];
        a1 += h3[(size_t)(m + 4) * 64 + lane];
        a2 += h3[(size_t)(m + 8) * 64 + lane];
        a3 += h3[(size_t)(m + 12) * 64 + lane];
    }
    for (; m < end; m += 4) a0 += h3[(size_t)m * 64 + lane];
    __shared__ float sh[4][64];
    sh[w][lane] = (a0 + a1) + (a2 + a3);
    __syncthreads();
    if (w == 0) {
        float v = (sh[0][lane] + sh[1][lane]) + (sh[2][lane] + sh[3][lane]);
        float cnt = (float)(end - start);
        v = (v / fmaxf(cnt, 1.0f)) * Wfc[lane];
#pragma unroll
        for (int off = 32; off > 0; off >>= 1) v += __shfl_down(v, off, 64);
        if (lane == 0) out[g] = 1.0f / (1.0f + expf(-(v + bfc[0])));
    }
}

static inline int cdiv(long long a, int b) { return (int)((a + b - 1) / b); }

extern "C" void kernel_launch(void* const* d_in, const int* in_sizes, int n_in,
                              void* d_out, int out_size, void* d_ws, size_t ws_size,
                              hipStream_t stream) {
    const float* x   = (const float*)d_in[0];
    const int*   ei  = (const int*)d_in[1];
    const int*   bat = (const int*)d_in[2];
    const float* W1  = (const float*)d_in[3];
    const float* b1  = (const float*)d_in[4];
    const float* W2  = (const float*)d_in[5];
    const float* b2  = (const float*)d_in[6];
    const float* W3  = (const float*)d_in[7];
    const float* b3  = (const float*)d_in[8];
    const float* Wfc = (const float*)d_in[9];
    const float* bfc = (const float*)d_in[10];
    float* out = (float*)d_out;

    const int N = in_sizes[0] / 5;   // 100000
    const int E = in_sizes[1] / 2;   // 1600000
    const int* src = ei;
    const int* dst = ei + E;

    // ---- workspace layout ----
    float* ws     = (float*)d_ws;
    float* dinv   = ws;                          // N
    int*   rowptr = (int*)(dinv + N);            // N+4
    int*   bcur   = rowptr + N + 4;              // NBK
    int*   csrs   = bcur + NBK;                  // E (src only)
    float* A      = (float*)(csrs + E);          // N*128 floats
    float* B      = A + (size_t)N * 128;         // N*128 floats
    // aliases (strictly sequential lifetimes):
    unsigned* stage = (unsigned*)A;              // 7.3MB, dead after fillB2
    float*    z1    = A;                         // N*5 fp32
    unsigned* h1bf  = (unsigned*)B;              // N*32 (bf16, dinv-folded)
    float*    z2    = A;                         // N*64 fp32 (z1 dead)
    float*    h2    = B;                         // N*128 fp32 (h1bf dead)
    unsigned* t3bf  = (unsigned*)A;              // N*32 bf16 (z2 dead)
    float*    h3    = B;                         // N*64 fp32 (h2 dead)

    const int Blk = 256;

    // ---- CSR build: bucket sort -> fused hist/scan/dinv/scatter ----
    zero_bcur<<<2, 256, 0, stream>>>(bcur);
    bucketA<<<512, 256, 0, stream>>>(src, dst, bcur, stage, E, N);
    fillB2<<<NBK, 256, 0, stream>>>(stage, bcur, rowptr, dinv, csrs, N, E);

    // ---- layer 1: aggregate raw x (5-dim); 5->64 +bias+relu ->bf16*dinv --
    gather5<<<cdiv(N, Blk), Blk, 0, stream>>>(rowptr, csrs, dinv, x, z1, N);
    transformB5<64, true, true, true, 2>
        <<<cdiv((long long)cdiv(N, 2) * 8, Blk), Blk, 0, stream>>>(
        z1, W1, b1, dinv, h1bf, N);

    // ---- layer 2: gather bf16 h1 -> z2 (fp32); 64->128 +bias+relu (fp32) --
    gatherBF<false><<<cdiv((long long)N * 8, Blk), Blk, 0, stream>>>(
        rowptr, csrs, dinv, nullptr, h1bf, z2, N);
    transformB<64, 128, true, false, false, 2>
        <<<cdiv((long long)cdiv(N, 2) * 16, Blk), Blk, 0, stream>>>(
        z2, W2, b2, nullptr, h2, N);

    // ---- layer 3: 128->64 ->bf16*dinv; gather +bias+relu -> fp32 h3 ----
    transformB<128, 64, false, true, true, 2>
        <<<cdiv((long long)cdiv(N, 2) * 8, Blk), Blk, 0, stream>>>(
        h2, W3, nullptr, dinv, t3bf, N);
    gatherBF<true><<<cdiv((long long)N * 8, Blk), Blk, 0, stream>>>(
        rowptr, csrs, dinv, b3, t3bf, h3, N);

    // ---- pooling + FC head ----
    pool<<<NG, 256, 0, stream>>>(h3, bat, Wfc, bfc, out, N);
}

// Round 15
// 379.943 us; speedup vs baseline: 1.1164x; 1.1164x over previous
//
#include <hip/hip_runtime.h>
#include <math.h>

#define NG 256
#define NBK 512          // sort buckets
#define BCAP 3584        // per-bucket staging capacity (mean 3125, +8 sigma)

static __device__ __forceinline__ int bucket_lo(int p, int n) {
    return (int)(((long long)p * n + NBK - 1) / NBK);   // ceil(p*n/NBK)
}

// ---- bf16 helpers (tables stored as packed pairs in uint) ----
static __device__ __forceinline__ float blo(unsigned u) {
    return __uint_as_float(u << 16);
}
static __device__ __forceinline__ float bhi(unsigned u) {
    return __uint_as_float(u & 0xFFFF0000u);
}
static __device__ __forceinline__ unsigned packbf(float a, float b) {
    unsigned ua = __float_as_uint(a);
    ua = (ua + 0x7FFFu + ((ua >> 16) & 1u)) >> 16;          // RNE, low half
    unsigned ub = __float_as_uint(b);
    ub = (ub + 0x7FFFu + ((ub >> 16) & 1u)) & 0xFFFF0000u;  // RNE, high half
    return ua | ub;
}

// ---------------- bucket cursor init ----------------
__global__ void zero_bcur(int* bcur) {
    int i = blockIdx.x * blockDim.x + threadIdx.x;
    if (i < NBK) bcur[i] = i * BCAP;
}

// ------- phase A: bucket edges by dst; staged record = (src<<8)|local_dst --
__global__ void bucketA(const int* __restrict__ src, const int* __restrict__ dst,
                        int* bcur, unsigned* stage, int e, int n) {
    __shared__ int cnt[NBK];
    __shared__ int base[NBK];
    int nb = gridDim.x;
    int c0 = (int)((long long)blockIdx.x * e / nb);
    int c1 = (int)((long long)(blockIdx.x + 1) * e / nb);
    for (int k = threadIdx.x; k < NBK; k += blockDim.x) cnt[k] = 0;
    __syncthreads();
    for (int i = c0 + threadIdx.x; i < c1; i += blockDim.x) {
        int d = dst[i];
        int p = (int)((long long)d * NBK / n);
        atomicAdd(&cnt[p], 1);
    }
    __syncthreads();
    for (int k = threadIdx.x; k < NBK; k += blockDim.x)
        base[k] = atomicAdd(&bcur[k], cnt[k]);
    __syncthreads();
    for (int k = threadIdx.x; k < NBK; k += blockDim.x) cnt[k] = 0;
    __syncthreads();
    for (int i = c0 + threadIdx.x; i < c1; i += blockDim.x) {
        int s = src[i], d = dst[i];
        int p = (int)((long long)d * NBK / n);
        int ldst = d - bucket_lo(p, n);           // < 196, fits 8 bits
        int lp = atomicAdd(&cnt[p], 1);
        stage[base[p] + lp] = ((unsigned)s << 8) | (unsigned)ldst;
    }
}

// ======= fused CSR finish: hist + scan + rowptr + dinv + scatter ========
__global__ void fillB2(const unsigned* __restrict__ stage,
                       const int* __restrict__ bcur,
                       int* __restrict__ rowptr, float* __restrict__ dinv,
                       int* __restrict__ csrs, int n, int e) {
    __shared__ int ldeg[256];
    __shared__ int loff[256];
    __shared__ int bstart;
    int p = blockIdx.x;
    int t = threadIdx.x;
    int lo = bucket_lo(p, n), hi = bucket_lo(p + 1, n);
    int nloc = hi - lo;                           // <= 196

    // ---- bucketStart[p] = sum of counts of buckets < p ----
    {
        int acc = 0;
        for (int k = t; k < p; k += 256) acc += bcur[k] - k * BCAP;
        ldeg[t] = acc;
        __syncthreads();
        for (int off = 128; off > 0; off >>= 1) {
            if (t < off) ldeg[t] += ldeg[t + off];
            __syncthreads();
        }
        if (t == 0) bstart = ldeg[0];
        __syncthreads();
    }

    // ---- local degree histogram ----
    if (t < 256) ldeg[t] = 0;
    __syncthreads();
    int s0 = p * BCAP, s1 = bcur[p];
    for (int i = s0 + t; i < s1; i += 256)
        atomicAdd(&ldeg[stage[i] & 255u], 1);
    __syncthreads();

    // ---- exclusive scan (256-wide) -> rowptr, dinv, cursors ----
    int v = (t < nloc) ? ldeg[t] : 0;
    loff[t] = v;
    __syncthreads();
    for (int off = 1; off < 256; off <<= 1) {
        int u = (t >= off) ? loff[t - off] : 0;
        __syncthreads();
        loff[t] += u;
        __syncthreads();
    }
    if (t < nloc) {
        int start = bstart + loff[t] - v;         // exclusive
        rowptr[lo + t] = start;
        dinv[lo + t] = rsqrtf((float)v + 1.0f);   // +1 self-loop
    }
    if (p == NBK - 1 && t == 0) rowptr[n] = e;
    __syncthreads();
    if (t < nloc) ldeg[t] = bstart + loff[t] - v; // reuse as cursors
    __syncthreads();

    // ---- scatter ----
    for (int i = s0 + t; i < s1; i += 256) {
        unsigned pk = stage[i];
        int ldst = (int)(pk & 255u);
        int pos = atomicAdd(&ldeg[ldst], 1);
        csrs[pos] = (int)(pk >> 8);
    }
}

// ---------------- layer-1 aggregate on raw x (5-dim), thread = node ------
__global__ void gather5(const int* __restrict__ rowptr,
                        const int* __restrict__ csrs,
                        const float* __restrict__ dinv,
                        const float* __restrict__ x,
                        float* __restrict__ z, int n) {
    int i = blockIdx.x * blockDim.x + threadIdx.x;
    if (i >= n) return;
    float di = dinv[i];
    float ws = di * di;
    const float* xr = x + (size_t)i * 5;
    float4 x4 = *(const float4*)(xr);
    float a0 = x4.x * ws, a1 = x4.y * ws, a2 = x4.z * ws,
          a3 = x4.w * ws, a4 = xr[4] * ws;
    int end = rowptr[i + 1];
    for (int j = rowptr[i]; j < end; ++j) {
        int s = csrs[j];
        float w = dinv[s] * di;
        const float* r = x + (size_t)s * 5;
        float4 r4 = *(const float4*)(r);
        float r1 = r[4];
        a0 = fmaf(w, r4.x, a0);
        a1 = fmaf(w, r4.y, a1);
        a2 = fmaf(w, r4.z, a2);
        a3 = fmaf(w, r4.w, a3);
        a4 = fmaf(w, r1, a4);
    }
    float* zr = z + (size_t)i * 5;
    zr[0] = a0; zr[1] = a1; zr[2] = a2; zr[3] = a3; zr[4] = a4;
}

// ---- transform epilogue: bias/relu/scale + fp32 or packed-bf16 store ----
template<int DOUT, bool BR, bool SCALE, bool OUTBF>
static __device__ __forceinline__ void emit(float o[8], const float* b, int c,
                                            float dsc, void* out, int i) {
    if (BR) {
        float4 b0 = *(const float4*)(b + c * 8);
        float4 b1 = *(const float4*)(b + c * 8 + 4);
        o[0] = fmaxf(o[0] + b0.x, 0.f); o[1] = fmaxf(o[1] + b0.y, 0.f);
        o[2] = fmaxf(o[2] + b0.z, 0.f); o[3] = fmaxf(o[3] + b0.w, 0.f);
        o[4] = fmaxf(o[4] + b1.x, 0.f); o[5] = fmaxf(o[5] + b1.y, 0.f);
        o[6] = fmaxf(o[6] + b1.z, 0.f); o[7] = fmaxf(o[7] + b1.w, 0.f);
    }
    if (SCALE) {
#pragma unroll
        for (int q = 0; q < 8; ++q) o[q] *= dsc;
    }
    if (OUTBF) {
        uint4 pk;
        pk.x = packbf(o[0], o[1]); pk.y = packbf(o[2], o[3]);
        pk.z = packbf(o[4], o[5]); pk.w = packbf(o[6], o[7]);
        *(uint4*)((unsigned*)out + (size_t)i * (DOUT / 2) + c * 4) = pk;
    } else {
        float* op = (float*)out + (size_t)i * DOUT + c * 8;
        float4 o0 = {o[0], o[1], o[2], o[3]};
        float4 o1 = {o[4], o[5], o[6], o[7]};
        *(float4*)(op) = o0;
        *(float4*)(op + 4) = o1;
    }
}

// ------- dense transform, 8 outputs x NODES nodes per thread -------------
// global W float4 loads (L1/L2-hot); row loads software-pipelined
template<int K, int DOUT, bool BR, bool SCALE, bool OUTBF, int NODES>
__global__ void transformB(const float* __restrict__ xin,
                           const float* __restrict__ W,
                           const float* __restrict__ b,
                           const float* __restrict__ dinv,
                           void* __restrict__ out, int n) {
    const int C = DOUT / 8;
    int tid = blockIdx.x * blockDim.x + threadIdx.x;
    int grp = tid / C;
    int c = tid % C;
    int i0 = grp * NODES;
    if (i0 >= n) return;
    float acc[NODES][8];
#pragma unroll
    for (int nn = 0; nn < NODES; ++nn)
#pragma unroll
        for (int q = 0; q < 8; ++q) acc[nn][q] = 0.0f;

    static_assert(K % 4 == 0, "K multiple of 4");
    int idx[NODES];
#pragma unroll
    for (int nn = 0; nn < NODES; ++nn)
        idx[nn] = (i0 + nn < n) ? i0 + nn : n - 1;

    float4 r[NODES];
#pragma unroll
    for (int nn = 0; nn < NODES; ++nn)
        r[nn] = *(const float4*)(xin + (size_t)idx[nn] * K);

    for (int k0 = 0; k0 < K; k0 += 4) {
        float4 rn[NODES];
        if (k0 + 4 < K) {
#pragma unroll
            for (int nn = 0; nn < NODES; ++nn)
                rn[nn] = *(const float4*)(xin + (size_t)idx[nn] * K + k0 + 4);
        }
#pragma unroll
        for (int kk = 0; kk < 4; ++kk) {
            const float* wp = W + (size_t)(k0 + kk) * DOUT + c * 8;
            float4 w0 = *(const float4*)(wp);
            float4 w1 = *(const float4*)(wp + 4);
#pragma unroll
            for (int nn = 0; nn < NODES; ++nn) {
                float v = (&r[nn].x)[kk];
                acc[nn][0] = fmaf(v, w0.x, acc[nn][0]);
                acc[nn][1] = fmaf(v, w0.y, acc[nn][1]);
                acc[nn][2] = fmaf(v, w0.z, acc[nn][2]);
                acc[nn][3] = fmaf(v, w0.w, acc[nn][3]);
                acc[nn][4] = fmaf(v, w1.x, acc[nn][4]);
                acc[nn][5] = fmaf(v, w1.y, acc[nn][5]);
                acc[nn][6] = fmaf(v, w1.z, acc[nn][6]);
                acc[nn][7] = fmaf(v, w1.w, acc[nn][7]);
            }
        }
#pragma unroll
        for (int nn = 0; nn < NODES; ++nn) r[nn] = rn[nn];
    }
#pragma unroll
    for (int nn = 0; nn < NODES; ++nn) {
        if (i0 + nn >= n) break;
        float dsc = SCALE ? dinv[i0 + nn] : 1.0f;
        emit<DOUT, BR, SCALE, OUTBF>(acc[nn], b, c, dsc, out, i0 + nn);
    }
}

// ---- K=5 fp32-input transform (layer 1) --------------------------------
template<int DOUT, bool BR, bool SCALE, bool OUTBF, int NODES>
__global__ void transformB5(const float* __restrict__ xin,
                            const float* __restrict__ W,
                            const float* __restrict__ b,
                            const float* __restrict__ dinv,
                            void* __restrict__ out, int n) {
    const int C = DOUT / 8;
    int tid = blockIdx.x * blockDim.x + threadIdx.x;
    int grp = tid / C;
    int c = tid % C;
    int i0 = grp * NODES;
    if (i0 >= n) return;
    float r[NODES][5];
#pragma unroll
    for (int nn = 0; nn < NODES; ++nn) {
        int idx = i0 + nn < n ? i0 + nn : n - 1;
        const float* row = xin + (size_t)idx * 5;
#pragma unroll
        for (int k = 0; k < 5; ++k) r[nn][k] = row[k];
    }
    float acc[NODES][8];
#pragma unroll
    for (int nn = 0; nn < NODES; ++nn)
#pragma unroll
        for (int q = 0; q < 8; ++q) acc[nn][q] = 0.0f;
#pragma unroll
    for (int k = 0; k < 5; ++k) {
        const float* wp = W + (size_t)k * DOUT + c * 8;
        float4 w0 = *(const float4*)(wp);
        float4 w1 = *(const float4*)(wp + 4);
#pragma unroll
        for (int nn = 0; nn < NODES; ++nn) {
            float v = r[nn][k];
            acc[nn][0] = fmaf(v, w0.x, acc[nn][0]);
            acc[nn][1] = fmaf(v, w0.y, acc[nn][1]);
            acc[nn][2] = fmaf(v, w0.z, acc[nn][2]);
            acc[nn][3] = fmaf(v, w0.w, acc[nn][3]);
            acc[nn][4] = fmaf(v, w1.x, acc[nn][4]);
            acc[nn][5] = fmaf(v, w1.y, acc[nn][5]);
            acc[nn][6] = fmaf(v, w1.z, acc[nn][6]);
            acc[nn][7] = fmaf(v, w1.w, acc[nn][7]);
        }
    }
#pragma unroll
    for (int nn = 0; nn < NODES; ++nn) {
        if (i0 + nn >= n) break;
        float dsc = SCALE ? dinv[i0 + nn] : 1.0f;
        emit<DOUT, BR, SCALE, OUTBF>(acc[nn], b, c, dsc, out, i0 + nn);
    }
}

// ------- 64-dim gather from bf16 table (dinv pre-folded into table) ------
// z[i] = dinv[i] * (g[i] + sum_src g[s]);   8 lanes/node, 8 feats/lane
// 8-edge unroll (8 loads in flight), 4 accumulator sets
template<bool BR>
__global__ void gatherBF(const int* __restrict__ rowptr,
                         const int* __restrict__ csrs,
                         const float* __restrict__ dinv,
                         const float* __restrict__ b,
                         const unsigned* __restrict__ g,   // [n][32] packed bf16
                         float* __restrict__ z, int n) {
    int tid = blockIdx.x * blockDim.x + threadIdx.x;
    int i = tid >> 3;
    int c = tid & 7;
    if (i >= n) return;
    uint4 sv = *(const uint4*)(g + (size_t)i * 32 + c * 4);
    float a0[8], a1[8], a2[8], a3[8];
    a0[0] = blo(sv.x); a0[1] = bhi(sv.x); a0[2] = blo(sv.y); a0[3] = bhi(sv.y);
    a0[4] = blo(sv.z); a0[5] = bhi(sv.z); a0[6] = blo(sv.w); a0[7] = bhi(sv.w);
#pragma unroll
    for (int q = 0; q < 8; ++q) { a1[q] = 0.0f; a2[q] = 0.0f; a3[q] = 0.0f; }
    int j = rowptr[i], end = rowptr[i + 1];
    for (; j + 7 < end; j += 8) {
        uint4 v0 = *(const uint4*)(g + (size_t)csrs[j]     * 32 + c * 4);
        uint4 v1 = *(const uint4*)(g + (size_t)csrs[j + 1] * 32 + c * 4);
        uint4 v2 = *(const uint4*)(g + (size_t)csrs[j + 2] * 32 + c * 4);
        uint4 v3 = *(const uint4*)(g + (size_t)csrs[j + 3] * 32 + c * 4);
        uint4 v4 = *(const uint4*)(g + (size_t)csrs[j + 4] * 32 + c * 4);
        uint4 v5 = *(const uint4*)(g + (size_t)csrs[j + 5] * 32 + c * 4);
        uint4 v6 = *(const uint4*)(g + (size_t)csrs[j + 6] * 32 + c * 4);
        uint4 v7 = *(const uint4*)(g + (size_t)csrs[j + 7] * 32 + c * 4);
        a0[0] += blo(v0.x); a0[1] += bhi(v0.x); a0[2] += blo(v0.y); a0[3] += bhi(v0.y);
        a0[4] += blo(v0.z); a0[5] += bhi(v0.z); a0[6] += blo(v0.w); a0[7] += bhi(v0.w);
        a1[0] += blo(v1.x); a1[1] += bhi(v1.x); a1[2] += blo(v1.y); a1[3] += bhi(v1.y);
        a1[4] += blo(v1.z); a1[5] += bhi(v1.z); a1[6] += blo(v1.w); a1[7] += bhi(v1.w);
        a2[0] += blo(v2.x); a2[1] += bhi(v2.x); a2[2] += blo(v2.y); a2[3] += bhi(v2.y);
        a2[4] += blo(v2.z); a2[5] += bhi(v2.z); a2[6] += blo(v2.w); a2[7] += bhi(v2.w);
        a3[0] += blo(v3.x); a3[1] += bhi(v3.x); a3[2] += blo(v3.y); a3[3] += bhi(v3.y);
        a3[4] += blo(v3.z); a3[5] += bhi(v3.z); a3[6] += blo(v3.w); a3[7] += bhi(v3.w);
        a0[0] += blo(v4.x); a0[1] += bhi(v4.x); a0[2] += blo(v4.y); a0[3] += bhi(v4.y);
        a0[4] += blo(v4.z); a0[5] += bhi(v4.z); a0[6] += blo(v4.w); a0[7] += bhi(v4.w);
        a1[0] += blo(v5.x); a1[1] += bhi(v5.x); a1[2] += blo(v5.y); a1[3] += bhi(v5.y);
        a1[4] += blo(v5.z); a1[5] += bhi(v5.z); a1[6] += blo(v5.w); a1[7] += bhi(v5.w);
        a2[0] += blo(v6.x); a2[1] += bhi(v6.x); a2[2] += blo(v6.y); a2[3] += bhi(v6.y);
        a2[4] += blo(v6.z); a2[5] += bhi(v6.z); a2[6] += blo(v6.w); a2[7] += bhi(v6.w);
        a3[0] += blo(v7.x); a3[1] += bhi(v7.x); a3[2] += blo(v7.y); a3[3] += bhi(v7.y);
        a3[4] += blo(v7.z); a3[5] += bhi(v7.z); a3[6] += blo(v7.w); a3[7] += bhi(v7.w);
    }
    for (; j < end; ++j) {
        int s0 = csrs[j];
        uint4 v0 = *(const uint4*)(g + (size_t)s0 * 32 + c * 4);
        a0[0] += blo(v0.x); a0[1] += bhi(v0.x); a0[2] += blo(v0.y); a0[3] += bhi(v0.y);
        a0[4] += blo(v0.z); a0[5] += bhi(v0.z); a0[6] += blo(v0.w); a0[7] += bhi(v0.w);
    }
    float di = dinv[i];
    float o[8];
#pragma unroll
    for (int q = 0; q < 8; ++q) o[q] = di * ((a0[q] + a1[q]) + (a2[q] + a3[q]));
    if (BR) {
        float4 b0 = *(const float4*)(b + c * 8);
        float4 b1 = *(const float4*)(b + c * 8 + 4);
        o[0] = fmaxf(o[0] + b0.x, 0.f); o[1] = fmaxf(o[1] + b0.y, 0.f);
        o[2] = fmaxf(o[2] + b0.z, 0.f); o[3] = fmaxf(o[3] + b0.w, 0.f);
        o[4] = fmaxf(o[4] + b1.x, 0.f); o[5] = fmaxf(o[5] + b1.y, 0.f);
        o[6] = fmaxf(o[6] + b1.z, 0.f); o[7] = fmaxf(o[7] + b1.w, 0.f);
    }
    float* zp = z + (size_t)i * 64 + c * 8;
    float4 z0 = {o[0], o[1], o[2], o[3]};
    float4 z1 = {o[4], o[5], o[6], o[7]};
    *(float4*)(zp) = z0;
    *(float4*)(zp + 4) = z1;
}

// ------- pooling + FC + sigmoid: 4 waves per graph, LDS combine ---------
__global__ void pool(const float* __restrict__ h3, const int* __restrict__ batch,
                     const float* __restrict__ Wfc, const float* __restrict__ bfc,
                     float* __restrict__ out, int n) {
    int g = blockIdx.x;
    int lane = threadIdx.x & 63;
    int w = threadIdx.x >> 6;  // 0..3
    int lo = 0, hi = n;
    while (lo < hi) { int m = (lo + hi) >> 1; if (batch[m] < g) lo = m + 1; else hi = m; }
    int start = lo;
    hi = n;
    while (lo < hi) { int m = (lo + hi) >> 1; if (batch[m] < g + 1) lo = m + 1; else hi = m; }
    int end = lo;
    float a0 = 0.f, a1 = 0.f, a2 = 0.f, a3 = 0.f;
    int m = start + w;
    for (; m + 12 < end; m += 16) {
        a0 += h3[(size_t)m * 64 + lane];
        a1 += h3[(size_t)(m + 4) * 64 + lane];
        a2 += h3[(size_t)(m + 8) * 64 + lane];
        a3 += h3[(size_t)(m + 12) * 64 + lane];
    }
    for (; m < end; m += 4) a0 += h3[(size_t)m * 64 + lane];
    __shared__ float sh[4][64];
    sh[w][lane] = (a0 + a1) + (a2 + a3);
    __syncthreads();
    if (w == 0) {
        float v = (sh[0][lane] + sh[1][lane]) + (sh[2][lane] + sh[3][lane]);
        float cnt = (float)(end - start);
        v = (v / fmaxf(cnt, 1.0f)) * Wfc[lane];
#pragma unroll
        for (int off = 32; off > 0; off >>= 1) v += __shfl_down(v, off, 64);
        if (lane == 0) out[g] = 1.0f / (1.0f + expf(-(v + bfc[0])));
    }
}

static inline int cdiv(long long a, int b) { return (int)((a + b - 1) / b); }

extern "C" void kernel_launch(void* const* d_in, const int* in_sizes, int n_in,
                              void* d_out, int out_size, void* d_ws, size_t ws_size,
                              hipStream_t stream) {
    const float* x   = (const float*)d_in[0];
    const int*   ei  = (const int*)d_in[1];
    const int*   bat = (const int*)d_in[2];
    const float* W1  = (const float*)d_in[3];
    const float* b1  = (const float*)d_in[4];
    const float* W2  = (const float*)d_in[5];
    const float* b2  = (const float*)d_in[6];
    const float* W3  = (const float*)d_in[7];
    const float* b3  = (const float*)d_in[8];
    const float* Wfc = (const float*)d_in[9];
    const float* bfc = (const float*)d_in[10];
    float* out = (float*)d_out;

    const int N = in_sizes[0] / 5;   // 100000
    const int E = in_sizes[1] / 2;   // 1600000
    const int* src = ei;
    const int* dst = ei + E;

    // ---- workspace layout ----
    float* ws     = (float*)d_ws;
    float* dinv   = ws;                          // N
    int*   rowptr = (int*)(dinv + N);            // N+4
    int*   bcur   = rowptr + N + 4;              // NBK
    int*   csrs   = bcur + NBK;                  // E (src only)
    float* A      = (float*)(csrs + E);          // N*128 floats
    float* B      = A + (size_t)N * 128;         // N*128 floats
    // aliases (strictly sequential lifetimes):
    unsigned* stage = (unsigned*)A;              // 7.3MB, dead after fillB2
    float*    z1    = A;                         // N*5 fp32
    unsigned* h1bf  = (unsigned*)B;              // N*32 (bf16, dinv-folded)
    float*    z2    = A;                         // N*64 fp32 (z1 dead)
    float*    h2    = B;                         // N*128 fp32 (h1bf dead)
    unsigned* t3bf  = (unsigned*)A;              // N*32 bf16 (z2 dead)
    float*    h3    = B;                         // N*64 fp32 (h2 dead)

    const int Blk = 256;

    // ---- CSR build: bucket sort -> fused hist/scan/dinv/scatter ----
    zero_bcur<<<2, 256, 0, stream>>>(bcur);
    bucketA<<<256, 256, 0, stream>>>(src, dst, bcur, stage, E, N);
    fillB2<<<NBK, 256, 0, stream>>>(stage, bcur, rowptr, dinv, csrs, N, E);

    // ---- layer 1: aggregate raw x (5-dim); 5->64 +bias+relu ->bf16*dinv --
    gather5<<<cdiv(N, Blk), Blk, 0, stream>>>(rowptr, csrs, dinv, x, z1, N);
    transformB5<64, true, true, true, 2>
        <<<cdiv((long long)cdiv(N, 2) * 8, Blk), Blk, 0, stream>>>(
        z1, W1, b1, dinv, h1bf, N);

    // ---- layer 2: gather bf16 h1 -> z2 (fp32); 64->128 +bias+relu (fp32) --
    gatherBF<false><<<cdiv((long long)N * 8, Blk), Blk, 0, stream>>>(
        rowptr, csrs, dinv, nullptr, h1bf, z2, N);
    transformB<64, 128, true, false, false, 4>
        <<<cdiv((long long)cdiv(N, 4) * 16, Blk), Blk, 0, stream>>>(
        z2, W2, b2, nullptr, h2, N);

    // ---- layer 3: 128->64 ->bf16*dinv; gather +bias+relu -> fp32 h3 ----
    transformB<128, 64, false, true, true, 4>
        <<<cdiv((long long)cdiv(N, 4) * 8, Blk), Blk, 0, stream>>>(
        h2, W3, nullptr, dinv, t3bf, N);
    gatherBF<true><<<cdiv((long long)N * 8, Blk), Blk, 0, stream>>>(
        rowptr, csrs, dinv, b3, t3bf, h3, N);

    // ---- pooling + FC head ----
    pool<<<NG, 256, 0, stream>>>(h3, bat, Wfc, bfc, out, N);
}